// Round 10
// baseline (67.472 us; speedup 1.0000x reference)
//
#include <hip/hip_runtime.h>

#define NSWEEP 2

typedef float v2f __attribute__((ext_vector_type(2)));

// Canonical wave64 inclusive prefix-sum (AMD GCN scan sequence).
// row_shr:1/2/4/8 within 16-lane rows (bound_ctrl zero-fills), then
// row_bcast15 (0x142, row_mask 0xA) and row_bcast31 (0x143, row_mask 0xC).
__device__ __forceinline__ float scan64(float d) {
    d += __int_as_float(__builtin_amdgcn_update_dpp(0, __float_as_int(d), 0x111, 0xF, 0xF, true));
    d += __int_as_float(__builtin_amdgcn_update_dpp(0, __float_as_int(d), 0x112, 0xF, 0xF, true));
    d += __int_as_float(__builtin_amdgcn_update_dpp(0, __float_as_int(d), 0x114, 0xF, 0xF, true));
    d += __int_as_float(__builtin_amdgcn_update_dpp(0, __float_as_int(d), 0x118, 0xF, 0xF, true));
    d += __int_as_float(__builtin_amdgcn_update_dpp(0, __float_as_int(d), 0x142, 0xA, 0xF, true));
    d += __int_as_float(__builtin_amdgcn_update_dpp(0, __float_as_int(d), 0x143, 0xC, 0xF, true));
    return d;
}

// wave-uniform broadcast of lane 63 (VALU/SALU, no LDS round-trip like __shfl)
__device__ __forceinline__ float rdl63(float v) {
    return __int_as_float(__builtin_amdgcn_readlane(__float_as_int(v), 63));
}

__global__ __launch_bounds__(64, 2) void ode_wf64x2(
    const float* __restrict__ thr,   // B x (N+1)
    const float* __restrict__ DOD,   // B
    const float* __restrict__ Vav,   // B
    const float* __restrict__ C0,    // B
    const float* __restrict__ R0,    // B
    const float* __restrict__ W1,    // 10 x 5
    const float* __restrict__ b1,    // 10
    const float* __restrict__ W2,    // 5 x 10
    const float* __restrict__ b2,    // 5
    float* __restrict__ out,         // B x (N+1) x 2
    int B, int N)
{
    const int j  = threadIdx.x & 63;     // step-slot within a 64-step block
    const int r0 = blockIdx.x * 2;       // 2 rows per wave (ILP)
    if (r0 >= B) return;
    const int rows[2] = {r0, min(r0 + 1, B - 1)};  // odd-B: row B-1 done twice (benign)

    // tanh(p) = 1 - 2/(1+e^{2p}); fold 2*log2(e) into layer-1 so exp2 applies
    // directly, fold "+1" into c3/c4 and "-2" into wa/wb. Hidden units packed
    // (h, h+5) -> v_pk_* fp32. Row-independent weights shared across rows.
    const float k2 = 2.0f * 1.4426950408889634f;

    v2f w0k[5], w3k[5], w4k[5], wa[5], wb[5];   // shared
    v2f bw[2][5];                                // per-row (DOD/Vav folded)
    float c3 = b2[3], c4 = b2[4];
    {
        float dodv[2] = {DOD[rows[0]], DOD[rows[1]]};
        float vavv[2] = {Vav[rows[0]], Vav[rows[1]]};
#pragma unroll
        for (int i = 0; i < 5; ++i) {
#pragma unroll
            for (int p = 0; p < 2; ++p) {
                int h = i + 5 * p;
                float a0 = W1[h * 5 + 0];
                float a1 = W1[h * 5 + 1];
                float a2 = W1[h * 5 + 2];
                float a3 = W1[h * 5 + 3];
                float a4 = W1[h * 5 + 4];
                w0k[i][p] = k2 * a0;
                w3k[i][p] = k2 * a3;
                w4k[i][p] = k2 * a4;
                float v3 = W2[30 + h];
                float v4 = W2[40 + h];
                c3 += v3; c4 += v4;
                wa[i][p] = -2.0f * v3;
                wb[i][p] = -2.0f * v4;
#pragma unroll
                for (int r = 0; r < 2; ++r)
                    bw[r][i][p] = k2 * (b1[h] + a1 * dodv[r] + a2 * vavv[r]);
            }
        }
    }

    const float* trp[2];
    float2* orow[2];
    float y03[2], y04[2];
#pragma unroll
    for (int r = 0; r < 2; ++r) {
        trp[r]  = thr + (size_t)rows[r] * (size_t)(N + 1);
        orow[r] = (float2*)(out + (size_t)rows[r] * (size_t)(N + 1) * 2);
        y03[r] = C0[rows[r]];
        y04[r] = R0[rows[r]];
        if (j == 0) orow[r][0] = make_float2(y03[r], y04[r]);
    }

    // t for block 0 + block-base t
    float tj[2], tj1[2], t0[2];
#pragma unroll
    for (int r = 0; r < 2; ++r) {
        tj[r]  = trp[r][min(j, N)];
        tj1[r] = trp[r][min(j + 1, N)];
        t0[r]  = trp[r][0];
    }

    // bootstrap slope F(y0, t0) per row
    float F3p[2], F4p[2], dF3[2], dF4[2];
#pragma unroll
    for (int r = 0; r < 2; ++r) {
        v2f Fa = {c3, 0.f}, Fb = {c4, 0.f};
#pragma unroll
        for (int i = 0; i < 5; ++i) {
            v2f x = w3k[i] * y03[r] + (w4k[i] * y04[r] + (w0k[i] * t0[r] + bw[r][i]));
            v2f e; e.x = __builtin_amdgcn_exp2f(x.x); e.y = __builtin_amdgcn_exp2f(x.y);
            v2f A = e + 1.0f;
            v2f s; s.x = __builtin_amdgcn_rcpf(A.x); s.y = __builtin_amdgcn_rcpf(A.y);
            Fa += wa[i] * s;
            Fb += wb[i] * s;
        }
        F3p[r] = Fa.x + Fa.y; F4p[r] = Fb.x + Fb.y;
        dF3[r] = 0.f; dF4[r] = 0.f;
    }

    const int nblk = (N + 63) >> 6;
    const int gInt = max(0, (N + 1) / 64 - 1);   // blocks with unclamped loads/stores

    for (int g = 0; g < nblk; ++g) {
        const int base = g << 6;
        const int nb = base + 64;

        // prefetch next block's t (lands during the sweeps)
        float ptj[2], ptj1[2], pt0[2];
        if (g < gInt) {
#pragma unroll
            for (int r = 0; r < 2; ++r) {
                ptj[r]  = trp[r][nb + j];
                ptj1[r] = trp[r][nb + j + 1];
                pt0[r]  = trp[r][nb];
            }
        } else {
#pragma unroll
            for (int r = 0; r < 2; ++r) {
                ptj[r]  = trp[r][min(nb + j, N)];
                ptj1[r] = trp[r][min(nb + j + 1, N)];
                pt0[r]  = trp[r][min(nb, N)];
            }
        }

        float hj[2], z3[2], z4[2];
        v2f bwt[2][5];
#pragma unroll
        for (int r = 0; r < 2; ++r) {
            hj[r] = tj1[r] - tj[r];              // 0 on clamped lanes
#pragma unroll
            for (int i = 0; i < 5; ++i) bwt[r][i] = w0k[i] * tj[r] + bw[r][i];
            // 2nd-order predictor: z = y0 + dt*(F_prev + 0.5*dt*dF)
            float dt = tj[r] - t0[r];
            z3[r] = fmaf(dt, fmaf(0.5f * dt, dF3[r], F3p[r]), y03[r]);
            z4[r] = fmaf(dt, fmaf(0.5f * dt, dF4[r], F4p[r]), y04[r]);
        }

        float S3[2], S4[2], F3[2], F4[2];
#pragma unroll
        for (int m = 0; m < NSWEEP; ++m) {
            // two independent MLP evals -> ILP fills trans-pipe gaps
#pragma unroll
            for (int r = 0; r < 2; ++r) {
                v2f Fa = {c3, 0.f}, Fb = {c4, 0.f};
#pragma unroll
                for (int i = 0; i < 5; ++i) {
                    v2f x = w3k[i] * z3[r] + (w4k[i] * z4[r] + bwt[r][i]);
                    v2f e; e.x = __builtin_amdgcn_exp2f(x.x);
                           e.y = __builtin_amdgcn_exp2f(x.y);
                    v2f A = e + 1.0f;
                    v2f s; s.x = __builtin_amdgcn_rcpf(A.x);
                           s.y = __builtin_amdgcn_rcpf(A.y);
                    Fa += wa[i] * s;
                    Fb += wb[i] * s;
                }
                F3[r] = Fa.x + Fa.y; F4[r] = Fb.x + Fb.y;
            }
            // four independent 6-stage DPP scan chains interleave
            float d3[2], d4[2];
#pragma unroll
            for (int r = 0; r < 2; ++r) { d3[r] = hj[r] * F3[r]; d4[r] = hj[r] * F4[r]; }
#pragma unroll
            for (int r = 0; r < 2; ++r) { S3[r] = scan64(d3[r]); S4[r] = scan64(d4[r]); }
            if (m < NSWEEP - 1) {
#pragma unroll
                for (int r = 0; r < 2; ++r) {
                    z3[r] = y03[r] + (S3[r] - d3[r]);  // exclusive prefix
                    z4[r] = y04[r] + (S4[r] - d4[r]);
                }
            }
        }

        // lane j holds the state AFTER step base+j
        if (g < gInt) {
#pragma unroll
            for (int r = 0; r < 2; ++r)
                orow[r][base + j + 1] = make_float2(y03[r] + S3[r], y04[r] + S4[r]);
        } else if (base + j < N) {
#pragma unroll
            for (int r = 0; r < 2; ++r)
                orow[r][base + j + 1] = make_float2(y03[r] + S3[r], y04[r] + S4[r]);
        }

        // carry via readlane (wave-uniform, no LDS latency on the serial path)
#pragma unroll
        for (int r = 0; r < 2; ++r) {
            float F3n = rdl63(F3[r]);
            float F4n = rdl63(F4[r]);
            y03[r] += rdl63(S3[r]);
            y04[r] += rdl63(S4[r]);
            float span = pt0[r] - t0[r];
            float inv = (span > 0.f) ? __builtin_amdgcn_rcpf(span) : 0.f;
            dF3[r] = (F3n - F3p[r]) * inv;
            dF4[r] = (F4n - F4p[r]) * inv;
            F3p[r] = F3n; F4p[r] = F4n;
            tj[r] = ptj[r]; tj1[r] = ptj1[r]; t0[r] = pt0[r];
        }
    }
}

extern "C" void kernel_launch(void* const* d_in, const int* in_sizes, int n_in,
                              void* d_out, int out_size, void* d_ws, size_t ws_size,
                              hipStream_t stream) {
    const float* thr = (const float*)d_in[0];
    const float* DOD = (const float*)d_in[1];
    const float* Vav = (const float*)d_in[2];
    const float* C0  = (const float*)d_in[3];
    const float* R0  = (const float*)d_in[4];
    const float* W1  = (const float*)d_in[5];
    const float* b1  = (const float*)d_in[6];
    const float* W2  = (const float*)d_in[7];
    const float* b2  = (const float*)d_in[8];
    float* out = (float*)d_out;

    int B = in_sizes[1];             // DOD is (1,B)
    int N = in_sizes[0] / B - 1;     // throughput is (B, N+1)

    dim3 block(64);
    dim3 grid((B + 1) / 2);          // 2 rows per 64-thread wave
    ode_wf64x2<<<grid, block, 0, stream>>>(thr, DOD, Vav, C0, R0,
                                           W1, b1, W2, b2, out, B, N);
}